// Round 1
// baseline (1389.496 us; speedup 1.0000x reference)
//
#include <hip/hip_runtime.h>
#include <hip/hip_bf16.h>

#define N_H_NODES 50000
#define N_G_NODES 50000
#define N_EDGES   1600000
#define N_GRAPHS  16

typedef __bf16 bf16;
typedef __bf16 bf16x8 __attribute__((ext_vector_type(8)));
typedef __bf16 bf16x4 __attribute__((ext_vector_type(4)));
typedef float  f32x4  __attribute__((ext_vector_type(4)));

__device__ __forceinline__ bf16 f2b(float f) { return (bf16)f; }

// ---------------------------------------------------------------------------
// Weight fp32 -> bf16 pre-convert (runs every launch; ws is re-poisoned)
// ---------------------------------------------------------------------------
__global__ void convert_weights(const float* __restrict__ W1a, const float* __restrict__ W1b,
                                const float* __restrict__ W2a, const float* __restrict__ W2b,
                                bf16* __restrict__ o1a, bf16* __restrict__ o1b,
                                bf16* __restrict__ o2a, bf16* __restrict__ o2b)
{
    const int i = blockIdx.x * 256 + threadIdx.x;
    if (i < 128 * 128) {
        o1a[i] = f2b(W1a[i]);
        o1b[i] = f2b(W1b[i]);
        o2b[i] = f2b(W2b[i]);
    }
    if (i < 128 * 320) o2a[i] = f2b(W2a[i]);
}

// ---------------------------------------------------------------------------
// Edge MLP + atomic scatter-sum.
// Per block: 128 edges, A-tile = [x_h[src] | edge_attr] (128x128),
// h1 = leaky(A @ W1a^T + b1a); h2 = h1 @ W1b^T + b1b; atomicAdd into a[tgt].
// MFMA 16x16x32 bf16; wave w handles rows [32w,32w+32) x all 128 cols.
// LDS pad +8 bf16 (stride 136): frag-read bank rotation 4 -> 2-way only (free).
// ---------------------------------------------------------------------------
__global__ __launch_bounds__(256, 2) void edge_mlp_scatter(
    const float* __restrict__ x_h, const float* __restrict__ edge_attr,
    const float* __restrict__ b1a, const float* __restrict__ b1b,
    const bf16* __restrict__ W1a, const bf16* __restrict__ W1b,
    const int* __restrict__ src, const int* __restrict__ tgt,
    float* __restrict__ a_out)
{
    constexpr int LDA = 136;
    __shared__ __align__(16) bf16 Af[128 * LDA];   // A tile, then h1 tile
    __shared__ __align__(16) bf16 Wf[128 * LDA];   // W1a, then W1b
    __shared__ int src_s[128];
    __shared__ int tgt_s[128];

    const int t = threadIdx.x;
    const long e0 = (long)blockIdx.x * 128;

    if (t < 128) { src_s[t] = src[e0 + t]; tgt_s[t] = tgt[e0 + t]; }

    // stage W1a: 128 rows x 128 bf16, 2 threads per row, 8x 16B each
    {
        const int row = t >> 1, seg = t & 1;
        const uint4* gsrc = (const uint4*)(W1a + row * 128 + seg * 64);
        uint4* ldst = (uint4*)(&Wf[row * LDA + seg * 64]);
        #pragma unroll
        for (int i = 0; i < 8; ++i) ldst[i] = gsrc[i];
    }
    __syncthreads();   // src_s ready

    // stage A: 128 rows x 128 f32 -> bf16; 32 threads/row (16 x_h | 16 edge_attr)
    {
        const int c4 = t & 31;
        const int r0 = t >> 5;
        #pragma unroll
        for (int p = 0; p < 16; ++p) {
            const int row = r0 + p * 8;
            float4 v;
            if (c4 < 16) {
                v = *(const float4*)(x_h + (long)src_s[row] * 64 + c4 * 4);
            } else {
                v = *(const float4*)(edge_attr + (e0 + row) * 64 + (c4 - 16) * 4);
            }
            bf16x4 b = {f2b(v.x), f2b(v.y), f2b(v.z), f2b(v.w)};
            *(bf16x4*)(&Af[row * LDA + c4 * 4]) = b;
        }
    }
    __syncthreads();

    const int wave = t >> 6;
    const int lane = t & 63;
    const int col  = lane & 15;
    const int quad = lane >> 4;

    f32x4 acc[2][8];
    #pragma unroll
    for (int mi = 0; mi < 2; ++mi)
        #pragma unroll
        for (int ni = 0; ni < 8; ++ni)
            acc[mi][ni] = (f32x4){0.f, 0.f, 0.f, 0.f};

    // GEMM1: h1 = A @ W1a^T
    #pragma unroll
    for (int ks = 0; ks < 4; ++ks) {
        bf16x8 av[2], bv[8];
        #pragma unroll
        for (int mi = 0; mi < 2; ++mi)
            av[mi] = *(const bf16x8*)(&Af[(wave * 32 + mi * 16 + col) * LDA + ks * 32 + quad * 8]);
        #pragma unroll
        for (int ni = 0; ni < 8; ++ni)
            bv[ni] = *(const bf16x8*)(&Wf[(ni * 16 + col) * LDA + ks * 32 + quad * 8]);
        #pragma unroll
        for (int mi = 0; mi < 2; ++mi)
            #pragma unroll
            for (int ni = 0; ni < 8; ++ni)
                acc[mi][ni] = __builtin_amdgcn_mfma_f32_16x16x32_bf16(av[mi], bv[ni], acc[mi][ni], 0, 0, 0);
    }
    __syncthreads();   // all waves done reading Af/Wf

    // load W1b into Wf
    {
        const int row = t >> 1, seg = t & 1;
        const uint4* gsrc = (const uint4*)(W1b + row * 128 + seg * 64);
        uint4* ldst = (uint4*)(&Wf[row * LDA + seg * 64]);
        #pragma unroll
        for (int i = 0; i < 8; ++i) ldst[i] = gsrc[i];
    }
    // epilogue 1: bias + leaky -> h1 (bf16) into Af
    #pragma unroll
    for (int ni = 0; ni < 8; ++ni) {
        const float bias = b1a[ni * 16 + col];
        #pragma unroll
        for (int mi = 0; mi < 2; ++mi) {
            #pragma unroll
            for (int r = 0; r < 4; ++r) {
                float v = acc[mi][ni][r] + bias;
                v = (v >= 0.f) ? v : 0.1f * v;
                const int row = wave * 32 + mi * 16 + quad * 4 + r;
                Af[row * LDA + ni * 16 + col] = f2b(v);
            }
        }
    }
    __syncthreads();

    // GEMM2: h2 = h1 @ W1b^T
    #pragma unroll
    for (int mi = 0; mi < 2; ++mi)
        #pragma unroll
        for (int ni = 0; ni < 8; ++ni)
            acc[mi][ni] = (f32x4){0.f, 0.f, 0.f, 0.f};
    #pragma unroll
    for (int ks = 0; ks < 4; ++ks) {
        bf16x8 av[2], bv[8];
        #pragma unroll
        for (int mi = 0; mi < 2; ++mi)
            av[mi] = *(const bf16x8*)(&Af[(wave * 32 + mi * 16 + col) * LDA + ks * 32 + quad * 8]);
        #pragma unroll
        for (int ni = 0; ni < 8; ++ni)
            bv[ni] = *(const bf16x8*)(&Wf[(ni * 16 + col) * LDA + ks * 32 + quad * 8]);
        #pragma unroll
        for (int mi = 0; mi < 2; ++mi)
            #pragma unroll
            for (int ni = 0; ni < 8; ++ni)
                acc[mi][ni] = __builtin_amdgcn_mfma_f32_16x16x32_bf16(av[mi], bv[ni], acc[mi][ni], 0, 0, 0);
    }

    // epilogue 2: bias + atomic scatter-sum (fp32, device scope)
    #pragma unroll
    for (int ni = 0; ni < 8; ++ni) {
        const float bias = b1b[ni * 16 + col];
        #pragma unroll
        for (int mi = 0; mi < 2; ++mi) {
            #pragma unroll
            for (int r = 0; r < 4; ++r) {
                const int row = wave * 32 + mi * 16 + quad * 4 + r;
                const float v = acc[mi][ni][r] + bias;
                atomicAdd(&a_out[(long)tgt_s[row] * 128 + ni * 16 + col], v);
            }
        }
    }
}

// ---------------------------------------------------------------------------
// Node MLP: in = [x_g | a | u[batch_g]] (K=320) -> leaky(in @ W2a^T + b2a)
//           -> @ W2b^T + b2b -> out.  Weights read from global (L2-resident).
// ---------------------------------------------------------------------------
__global__ __launch_bounds__(256, 1) void node_mlp(
    const float* __restrict__ x_g, const float* __restrict__ u,
    const float* __restrict__ b2a, const float* __restrict__ b2b,
    const bf16* __restrict__ W2a, const bf16* __restrict__ W2b,
    const int* __restrict__ batch_g, const float* __restrict__ a_in,
    float* __restrict__ out)
{
    constexpr int LDI = 328;   // 320 + 8 pad
    constexpr int LDH = 136;
    __shared__ __align__(16) bf16 In[128 * LDI];
    __shared__ __align__(16) bf16 H1[128 * LDH];

    const int t = threadIdx.x;
    const int n0 = blockIdx.x * 128;

    // stage input: 128 rows x 320 f32 (80 float4/row), flat-indexed
    for (int idx = t; idx < 128 * 80; idx += 256) {
        const int row = idx / 80;
        const int c4 = idx - row * 80;
        const int g = min(n0 + row, N_G_NODES - 1);
        float4 v;
        if (c4 < 32)      v = *(const float4*)(x_g + (long)g * 128 + c4 * 4);
        else if (c4 < 64) v = *(const float4*)(a_in + (long)g * 128 + (c4 - 32) * 4);
        else              v = *(const float4*)(u + (long)batch_g[g] * 64 + (c4 - 64) * 4);
        bf16x4 b = {f2b(v.x), f2b(v.y), f2b(v.z), f2b(v.w)};
        *(bf16x4*)(&In[row * LDI + c4 * 4]) = b;
    }
    __syncthreads();

    const int wave = t >> 6;
    const int lane = t & 63;
    const int col  = lane & 15;
    const int quad = lane >> 4;

    f32x4 acc[2][8];
    #pragma unroll
    for (int mi = 0; mi < 2; ++mi)
        #pragma unroll
        for (int ni = 0; ni < 8; ++ni)
            acc[mi][ni] = (f32x4){0.f, 0.f, 0.f, 0.f};

    // GEMM1: K=320
    #pragma unroll
    for (int ks = 0; ks < 10; ++ks) {
        bf16x8 av[2], bv[8];
        #pragma unroll
        for (int mi = 0; mi < 2; ++mi)
            av[mi] = *(const bf16x8*)(&In[(wave * 32 + mi * 16 + col) * LDI + ks * 32 + quad * 8]);
        #pragma unroll
        for (int ni = 0; ni < 8; ++ni)
            bv[ni] = *(const bf16x8*)(W2a + (long)(ni * 16 + col) * 320 + ks * 32 + quad * 8);
        #pragma unroll
        for (int mi = 0; mi < 2; ++mi)
            #pragma unroll
            for (int ni = 0; ni < 8; ++ni)
                acc[mi][ni] = __builtin_amdgcn_mfma_f32_16x16x32_bf16(av[mi], bv[ni], acc[mi][ni], 0, 0, 0);
    }

    // epilogue 1 -> H1
    #pragma unroll
    for (int ni = 0; ni < 8; ++ni) {
        const float bias = b2a[ni * 16 + col];
        #pragma unroll
        for (int mi = 0; mi < 2; ++mi) {
            #pragma unroll
            for (int r = 0; r < 4; ++r) {
                float v = acc[mi][ni][r] + bias;
                v = (v >= 0.f) ? v : 0.1f * v;
                const int row = wave * 32 + mi * 16 + quad * 4 + r;
                H1[row * LDH + ni * 16 + col] = f2b(v);
            }
        }
    }
    __syncthreads();

    // GEMM2: K=128
    #pragma unroll
    for (int mi = 0; mi < 2; ++mi)
        #pragma unroll
        for (int ni = 0; ni < 8; ++ni)
            acc[mi][ni] = (f32x4){0.f, 0.f, 0.f, 0.f};
    #pragma unroll
    for (int ks = 0; ks < 4; ++ks) {
        bf16x8 av[2], bv[8];
        #pragma unroll
        for (int mi = 0; mi < 2; ++mi)
            av[mi] = *(const bf16x8*)(&H1[(wave * 32 + mi * 16 + col) * LDH + ks * 32 + quad * 8]);
        #pragma unroll
        for (int ni = 0; ni < 8; ++ni)
            bv[ni] = *(const bf16x8*)(W2b + (long)(ni * 16 + col) * 128 + ks * 32 + quad * 8);
        #pragma unroll
        for (int mi = 0; mi < 2; ++mi)
            #pragma unroll
            for (int ni = 0; ni < 8; ++ni)
                acc[mi][ni] = __builtin_amdgcn_mfma_f32_16x16x32_bf16(av[mi], bv[ni], acc[mi][ni], 0, 0, 0);
    }

    // epilogue 2: bias + store (row-guarded)
    #pragma unroll
    for (int ni = 0; ni < 8; ++ni) {
        const float bias = b2b[ni * 16 + col];
        #pragma unroll
        for (int mi = 0; mi < 2; ++mi) {
            #pragma unroll
            for (int r = 0; r < 4; ++r) {
                const int row = wave * 32 + mi * 16 + quad * 4 + r;
                const int grow = n0 + row;
                if (grow < N_G_NODES)
                    out[(long)grow * 128 + ni * 16 + col] = acc[mi][ni][r] + bias;
            }
        }
    }
}

// ---------------------------------------------------------------------------
extern "C" void kernel_launch(void* const* d_in, const int* in_sizes, int n_in,
                              void* d_out, int out_size, void* d_ws, size_t ws_size,
                              hipStream_t stream)
{
    const float* x_h  = (const float*)d_in[0];
    const float* x_g  = (const float*)d_in[1];
    const float* edge_attr = (const float*)d_in[2];
    const float* u    = (const float*)d_in[3];
    const float* W1a  = (const float*)d_in[4];
    const float* b1a  = (const float*)d_in[5];
    const float* W1b  = (const float*)d_in[6];
    const float* b1b  = (const float*)d_in[7];
    const float* W2a  = (const float*)d_in[8];
    const float* b2a  = (const float*)d_in[9];
    const float* W2b  = (const float*)d_in[10];
    const float* b2b  = (const float*)d_in[11];
    const int* edge_index = (const int*)d_in[12];   // [2, E]
    const int* batch_g    = (const int*)d_in[13];
    const int* src = edge_index;
    const int* tgt = edge_index + N_EDGES;

    char* ws = (char*)d_ws;
    float* a_acc = (float*)ws;
    size_t off = (size_t)N_G_NODES * 128 * sizeof(float);
    bf16* w1a = (bf16*)(ws + off); off += (size_t)128 * 128 * sizeof(bf16);
    bf16* w1b = (bf16*)(ws + off); off += (size_t)128 * 128 * sizeof(bf16);
    bf16* w2a = (bf16*)(ws + off); off += (size_t)128 * 320 * sizeof(bf16);
    bf16* w2b = (bf16*)(ws + off);

    hipMemsetAsync(a_acc, 0, (size_t)N_G_NODES * 128 * sizeof(float), stream);
    convert_weights<<<160, 256, 0, stream>>>(W1a, W1b, W2a, W2b, w1a, w1b, w2a, w2b);
    edge_mlp_scatter<<<N_EDGES / 128, 256, 0, stream>>>(x_h, edge_attr, b1a, b1b,
                                                        w1a, w1b, src, tgt, a_acc);
    node_mlp<<<(N_G_NODES + 127) / 128, 256, 0, stream>>>(x_g, u, b2a, b2b,
                                                          w2a, w2b, batch_g, a_acc,
                                                          (float*)d_out);
}

// Round 2
// 1372.382 us; speedup vs baseline: 1.0125x; 1.0125x over previous
//
#include <hip/hip_runtime.h>
#include <hip/hip_bf16.h>

#define N_H_NODES 50000
#define N_G_NODES 50000
#define N_EDGES   1600000
#define N_GRAPHS  16

typedef __bf16 bf16;
typedef __bf16 bf16x8 __attribute__((ext_vector_type(8)));
typedef __bf16 bf16x4 __attribute__((ext_vector_type(4)));
typedef float  f32x4  __attribute__((ext_vector_type(4)));

__device__ __forceinline__ bf16 f2b(float f) { return (bf16)f; }

// ---------------------------------------------------------------------------
// Weight fp32 -> bf16 pre-convert (runs every launch; ws is re-poisoned)
// ---------------------------------------------------------------------------
__global__ void convert_weights(const float* __restrict__ W1a, const float* __restrict__ W1b,
                                const float* __restrict__ W2a, const float* __restrict__ W2b,
                                bf16* __restrict__ o1a, bf16* __restrict__ o1b,
                                bf16* __restrict__ o2a, bf16* __restrict__ o2b)
{
    const int i = blockIdx.x * 256 + threadIdx.x;
    if (i < 128 * 128) {
        o1a[i] = f2b(W1a[i]);
        o1b[i] = f2b(W1b[i]);
        o2b[i] = f2b(W2b[i]);
    }
    if (i < 128 * 320) o2a[i] = f2b(W2a[i]);
}

// ---------------------------------------------------------------------------
// Counting sort of edges by tgt: histogram -> exclusive scan -> scatter perm
// ---------------------------------------------------------------------------
__global__ void hist_kernel(const int* __restrict__ tgt, int* __restrict__ hist)
{
    const int e = blockIdx.x * 256 + threadIdx.x;
    if (e < N_EDGES) atomicAdd(&hist[tgt[e]], 1);
}

__global__ void scan_cursor(const int* __restrict__ hist, int* __restrict__ cursor)
{
    // single block, 1024 threads
    __shared__ int sums[1024];
    const int t = threadIdx.x;
    const int CH = (N_G_NODES + 1023) / 1024;   // 49
    const int base = t * CH;
    int s = 0;
    for (int i = 0; i < CH; ++i) {
        const int idx = base + i;
        if (idx < N_G_NODES) s += hist[idx];
    }
    sums[t] = s;
    __syncthreads();
    // Hillis-Steele inclusive scan
    for (int off = 1; off < 1024; off <<= 1) {
        int v = (t >= off) ? sums[t - off] : 0;
        __syncthreads();
        sums[t] += v;
        __syncthreads();
    }
    int run = sums[t] - s;  // exclusive prefix for this chunk
    for (int i = 0; i < CH; ++i) {
        const int idx = base + i;
        if (idx < N_G_NODES) {
            cursor[idx] = run;
            run += hist[idx];
        }
    }
}

__global__ void scatter_perm(const int* __restrict__ tgt, int* __restrict__ cursor,
                             int* __restrict__ perm, int* __restrict__ tgt_sorted)
{
    const int e = blockIdx.x * 256 + threadIdx.x;
    if (e < N_EDGES) {
        const int tg = tgt[e];
        const int p = atomicAdd(&cursor[tg], 1);
        perm[p] = e;
        tgt_sorted[p] = tg;
    }
}

// ---------------------------------------------------------------------------
// Edge MLP on tgt-sorted edges + in-block segmented reduction.
// Per block: 128 sorted edges; A = [x_h[src] | edge_attr] (128x128 bf16 LDS),
// h1 = leaky(A@W1a^T+b1a), h2 = h1@W1b^T+b1b -> fp32 LDS (overlaid) ->
// per-column segment scan over sorted tgt runs -> few wave-uniform atomics.
// ---------------------------------------------------------------------------
__global__ __launch_bounds__(256, 2) void edge_mlp_sorted(
    const float* __restrict__ x_h, const float* __restrict__ edge_attr,
    const float* __restrict__ b1a, const float* __restrict__ b1b,
    const bf16* __restrict__ W1a, const bf16* __restrict__ W1b,
    const int* __restrict__ src,
    const int* __restrict__ perm, const int* __restrict__ tgt_sorted,
    float* __restrict__ a_out)
{
    constexpr int LDA = 136;   // bf16 leading dim (pad 8)
    constexpr int LDH = 132;   // fp32 leading dim for h2 tile (pad 4)
    __shared__ __align__(16) char smem[128 * LDA * 2 * 2];  // 69632 B
    bf16*  Af  = (bf16*)smem;                       // 34816 B
    bf16*  Wf  = (bf16*)(smem + 128 * LDA * 2);     // 34816 B
    float* h2s = (float*)smem;                      // 67584 B overlay (after GEMMs)
    __shared__ int src_s[128];
    __shared__ int tgt_s[128];
    __shared__ int eid_s[128];

    const int t = threadIdx.x;
    const long e0 = (long)blockIdx.x * 128;

    if (t < 128) {
        const int e = perm[e0 + t];
        eid_s[t] = e;
        src_s[t] = src[e];
        tgt_s[t] = tgt_sorted[e0 + t];
    }

    // stage W1a: 2 threads/row, 8x 16B each
    {
        const int row = t >> 1, seg = t & 1;
        const uint4* gsrc = (const uint4*)(W1a + row * 128 + seg * 64);
        uint4* ldst = (uint4*)(&Wf[row * LDA + seg * 64]);
        #pragma unroll
        for (int i = 0; i < 8; ++i) ldst[i] = gsrc[i];
    }
    __syncthreads();   // src_s/eid_s ready

    // stage A: 32 threads/row (16 on x_h row, 16 on edge_attr row)
    {
        const int c4 = t & 31;
        const int r0 = t >> 5;
        #pragma unroll
        for (int p = 0; p < 16; ++p) {
            const int row = r0 + p * 8;
            float4 v;
            if (c4 < 16) {
                v = *(const float4*)(x_h + (long)src_s[row] * 64 + c4 * 4);
            } else {
                v = *(const float4*)(edge_attr + (long)eid_s[row] * 64 + (c4 - 16) * 4);
            }
            bf16x4 b = {f2b(v.x), f2b(v.y), f2b(v.z), f2b(v.w)};
            *(bf16x4*)(&Af[row * LDA + c4 * 4]) = b;
        }
    }
    __syncthreads();

    const int wave = t >> 6;
    const int lane = t & 63;
    const int col  = lane & 15;
    const int quad = lane >> 4;

    f32x4 acc[2][8];
    #pragma unroll
    for (int mi = 0; mi < 2; ++mi)
        #pragma unroll
        for (int ni = 0; ni < 8; ++ni)
            acc[mi][ni] = (f32x4){0.f, 0.f, 0.f, 0.f};

    // GEMM1: h1 = A @ W1a^T
    #pragma unroll
    for (int ks = 0; ks < 4; ++ks) {
        bf16x8 av[2], bv[8];
        #pragma unroll
        for (int mi = 0; mi < 2; ++mi)
            av[mi] = *(const bf16x8*)(&Af[(wave * 32 + mi * 16 + col) * LDA + ks * 32 + quad * 8]);
        #pragma unroll
        for (int ni = 0; ni < 8; ++ni)
            bv[ni] = *(const bf16x8*)(&Wf[(ni * 16 + col) * LDA + ks * 32 + quad * 8]);
        #pragma unroll
        for (int mi = 0; mi < 2; ++mi)
            #pragma unroll
            for (int ni = 0; ni < 8; ++ni)
                acc[mi][ni] = __builtin_amdgcn_mfma_f32_16x16x32_bf16(av[mi], bv[ni], acc[mi][ni], 0, 0, 0);
    }
    __syncthreads();

    // stage W1b; epilogue 1: bias + leaky -> h1 (bf16) into Af
    {
        const int row = t >> 1, seg = t & 1;
        const uint4* gsrc = (const uint4*)(W1b + row * 128 + seg * 64);
        uint4* ldst = (uint4*)(&Wf[row * LDA + seg * 64]);
        #pragma unroll
        for (int i = 0; i < 8; ++i) ldst[i] = gsrc[i];
    }
    #pragma unroll
    for (int ni = 0; ni < 8; ++ni) {
        const float bias = b1a[ni * 16 + col];
        #pragma unroll
        for (int mi = 0; mi < 2; ++mi) {
            #pragma unroll
            for (int r = 0; r < 4; ++r) {
                float v = acc[mi][ni][r] + bias;
                v = (v >= 0.f) ? v : 0.1f * v;
                const int row = wave * 32 + mi * 16 + quad * 4 + r;
                Af[row * LDA + ni * 16 + col] = f2b(v);
            }
        }
    }
    __syncthreads();

    // GEMM2: h2 = h1 @ W1b^T
    #pragma unroll
    for (int mi = 0; mi < 2; ++mi)
        #pragma unroll
        for (int ni = 0; ni < 8; ++ni)
            acc[mi][ni] = (f32x4){0.f, 0.f, 0.f, 0.f};
    #pragma unroll
    for (int ks = 0; ks < 4; ++ks) {
        bf16x8 av[2], bv[8];
        #pragma unroll
        for (int mi = 0; mi < 2; ++mi)
            av[mi] = *(const bf16x8*)(&Af[(wave * 32 + mi * 16 + col) * LDA + ks * 32 + quad * 8]);
        #pragma unroll
        for (int ni = 0; ni < 8; ++ni)
            bv[ni] = *(const bf16x8*)(&Wf[(ni * 16 + col) * LDA + ks * 32 + quad * 8]);
        #pragma unroll
        for (int mi = 0; mi < 2; ++mi)
            #pragma unroll
            for (int ni = 0; ni < 8; ++ni)
                acc[mi][ni] = __builtin_amdgcn_mfma_f32_16x16x32_bf16(av[mi], bv[ni], acc[mi][ni], 0, 0, 0);
    }
    __syncthreads();   // Af/Wf dead; safe to overlay h2s

    // h2 (+bias) -> fp32 LDS tile
    #pragma unroll
    for (int ni = 0; ni < 8; ++ni) {
        const float bias = b1b[ni * 16 + col];
        #pragma unroll
        for (int mi = 0; mi < 2; ++mi) {
            #pragma unroll
            for (int r = 0; r < 4; ++r) {
                const int row = wave * 32 + mi * 16 + quad * 4 + r;
                h2s[row * LDH + ni * 16 + col] = acc[mi][ni][r] + bias;
            }
        }
    }
    __syncthreads();

    // segmented reduction: thread owns (col, 64-row half); tgt runs are
    // wave-uniform (all lanes in a wave walk the same rows) -> coalesced,
    // wave-uniform atomic flushes, ~3 per thread.
    {
        const int c    = t & 127;
        const int rbeg = (t >> 7) * 64;
        float s = 0.f;
        int cur = tgt_s[rbeg];
        #pragma unroll 8
        for (int i = 0; i < 64; ++i) {
            const int row = rbeg + i;
            const int tg = tgt_s[row];
            if (tg != cur) {
                atomicAdd(&a_out[(long)cur * 128 + c], s);
                s = 0.f;
                cur = tg;
            }
            s += h2s[row * LDH + c];
        }
        atomicAdd(&a_out[(long)cur * 128 + c], s);
    }
}

// ---------------------------------------------------------------------------
// Node MLP: A-fragments built directly from global fp32 (x_g | a | u[batch]),
// weights read from L2-resident bf16; only H1 lives in LDS (34.8 KB -> 4 blk/CU)
// ---------------------------------------------------------------------------
__global__ __launch_bounds__(256, 4) void node_mlp2(
    const float* __restrict__ x_g, const float* __restrict__ u,
    const float* __restrict__ b2a, const float* __restrict__ b2b,
    const bf16* __restrict__ W2a, const bf16* __restrict__ W2b,
    const int* __restrict__ batch_g, const float* __restrict__ a_in,
    float* __restrict__ out)
{
    constexpr int LDH = 136;
    __shared__ __align__(16) bf16 H1[128 * LDH];

    const int t = threadIdx.x;
    const int n0 = blockIdx.x * 128;
    const int wave = t >> 6;
    const int lane = t & 63;
    const int col  = lane & 15;
    const int quad = lane >> 4;

    // per-lane row state for the 2 m-tiles
    int   grow[2];
    int   bg[2];
    #pragma unroll
    for (int mi = 0; mi < 2; ++mi) {
        const int r = n0 + wave * 32 + mi * 16 + col;
        grow[mi] = min(r, N_G_NODES - 1);
        bg[mi] = batch_g[grow[mi]];
    }

    f32x4 acc[2][8];
    #pragma unroll
    for (int mi = 0; mi < 2; ++mi)
        #pragma unroll
        for (int ni = 0; ni < 8; ++ni)
            acc[mi][ni] = (f32x4){0.f, 0.f, 0.f, 0.f};

    // GEMM1: K=320, A built on the fly
    #pragma unroll
    for (int ks = 0; ks < 10; ++ks) {
        const int k = ks * 32 + quad * 8;
        bf16x8 av[2], bv[8];
        #pragma unroll
        for (int mi = 0; mi < 2; ++mi) {
            const float* p;
            if (k < 128)      p = x_g  + (long)grow[mi] * 128 + k;
            else if (k < 256) p = a_in + (long)grow[mi] * 128 + (k - 128);
            else              p = u + bg[mi] * 64 + (k - 256);
            const float4 v0 = *(const float4*)p;
            const float4 v1 = *(const float4*)(p + 4);
            av[mi] = (bf16x8){f2b(v0.x), f2b(v0.y), f2b(v0.z), f2b(v0.w),
                              f2b(v1.x), f2b(v1.y), f2b(v1.z), f2b(v1.w)};
        }
        #pragma unroll
        for (int ni = 0; ni < 8; ++ni)
            bv[ni] = *(const bf16x8*)(W2a + (long)(ni * 16 + col) * 320 + k);
        #pragma unroll
        for (int mi = 0; mi < 2; ++mi)
            #pragma unroll
            for (int ni = 0; ni < 8; ++ni)
                acc[mi][ni] = __builtin_amdgcn_mfma_f32_16x16x32_bf16(av[mi], bv[ni], acc[mi][ni], 0, 0, 0);
    }

    // epilogue 1 -> H1 (bf16)
    #pragma unroll
    for (int ni = 0; ni < 8; ++ni) {
        const float bias = b2a[ni * 16 + col];
        #pragma unroll
        for (int mi = 0; mi < 2; ++mi) {
            #pragma unroll
            for (int r = 0; r < 4; ++r) {
                float v = acc[mi][ni][r] + bias;
                v = (v >= 0.f) ? v : 0.1f * v;
                const int row = wave * 32 + mi * 16 + quad * 4 + r;
                H1[row * LDH + ni * 16 + col] = f2b(v);
            }
        }
    }
    __syncthreads();

    // GEMM2: K=128
    #pragma unroll
    for (int mi = 0; mi < 2; ++mi)
        #pragma unroll
        for (int ni = 0; ni < 8; ++ni)
            acc[mi][ni] = (f32x4){0.f, 0.f, 0.f, 0.f};
    #pragma unroll
    for (int ks = 0; ks < 4; ++ks) {
        bf16x8 av[2], bv[8];
        #pragma unroll
        for (int mi = 0; mi < 2; ++mi)
            av[mi] = *(const bf16x8*)(&H1[(wave * 32 + mi * 16 + col) * LDH + ks * 32 + quad * 8]);
        #pragma unroll
        for (int ni = 0; ni < 8; ++ni)
            bv[ni] = *(const bf16x8*)(W2b + (long)(ni * 16 + col) * 128 + ks * 32 + quad * 8);
        #pragma unroll
        for (int mi = 0; mi < 2; ++mi)
            #pragma unroll
            for (int ni = 0; ni < 8; ++ni)
                acc[mi][ni] = __builtin_amdgcn_mfma_f32_16x16x32_bf16(av[mi], bv[ni], acc[mi][ni], 0, 0, 0);
    }

    // epilogue 2: bias + store (row-guarded)
    #pragma unroll
    for (int ni = 0; ni < 8; ++ni) {
        const float bias = b2b[ni * 16 + col];
        #pragma unroll
        for (int mi = 0; mi < 2; ++mi) {
            #pragma unroll
            for (int r = 0; r < 4; ++r) {
                const int row = wave * 32 + mi * 16 + quad * 4 + r;
                const int g = n0 + row;
                if (g < N_G_NODES)
                    out[(long)g * 128 + ni * 16 + col] = acc[mi][ni][r] + bias;
            }
        }
    }
}

// ---------------------------------------------------------------------------
extern "C" void kernel_launch(void* const* d_in, const int* in_sizes, int n_in,
                              void* d_out, int out_size, void* d_ws, size_t ws_size,
                              hipStream_t stream)
{
    const float* x_h  = (const float*)d_in[0];
    const float* x_g  = (const float*)d_in[1];
    const float* edge_attr = (const float*)d_in[2];
    const float* u    = (const float*)d_in[3];
    const float* W1a  = (const float*)d_in[4];
    const float* b1a  = (const float*)d_in[5];
    const float* W1b  = (const float*)d_in[6];
    const float* b1b  = (const float*)d_in[7];
    const float* W2a  = (const float*)d_in[8];
    const float* b2a  = (const float*)d_in[9];
    const float* W2b  = (const float*)d_in[10];
    const float* b2b  = (const float*)d_in[11];
    const int* edge_index = (const int*)d_in[12];   // [2, E]
    const int* batch_g    = (const int*)d_in[13];
    const int* src = edge_index;
    const int* tgt = edge_index + N_EDGES;

    char* ws = (char*)d_ws;
    size_t off = 0;
    float* a_acc = (float*)(ws + off); off += (size_t)N_G_NODES * 128 * sizeof(float);
    bf16* w1a = (bf16*)(ws + off); off += (size_t)128 * 128 * sizeof(bf16);
    bf16* w1b = (bf16*)(ws + off); off += (size_t)128 * 128 * sizeof(bf16);
    bf16* w2a = (bf16*)(ws + off); off += (size_t)128 * 320 * sizeof(bf16);
    bf16* w2b = (bf16*)(ws + off); off += (size_t)128 * 128 * sizeof(bf16);
    int* hist       = (int*)(ws + off); off += (size_t)N_G_NODES * sizeof(int);
    int* cursor     = (int*)(ws + off); off += (size_t)N_G_NODES * sizeof(int);
    int* perm       = (int*)(ws + off); off += (size_t)N_EDGES * sizeof(int);
    int* tgt_sorted = (int*)(ws + off); off += (size_t)N_EDGES * sizeof(int);

    hipMemsetAsync(a_acc, 0, (size_t)N_G_NODES * 128 * sizeof(float), stream);
    hipMemsetAsync(hist, 0, (size_t)N_G_NODES * sizeof(int), stream);

    convert_weights<<<160, 256, 0, stream>>>(W1a, W1b, W2a, W2b, w1a, w1b, w2a, w2b);
    hist_kernel<<<(N_EDGES + 255) / 256, 256, 0, stream>>>(tgt, hist);
    scan_cursor<<<1, 1024, 0, stream>>>(hist, cursor);
    scatter_perm<<<(N_EDGES + 255) / 256, 256, 0, stream>>>(tgt, cursor, perm, tgt_sorted);
    edge_mlp_sorted<<<N_EDGES / 128, 256, 0, stream>>>(x_h, edge_attr, b1a, b1b,
                                                       w1a, w1b, src, perm, tgt_sorted, a_acc);
    node_mlp2<<<(N_G_NODES + 127) / 128, 256, 0, stream>>>(x_g, u, b2a, b2b,
                                                           w2a, w2b, batch_g, a_acc,
                                                           (float*)d_out);
}

// Round 3
// 1324.405 us; speedup vs baseline: 1.0491x; 1.0362x over previous
//
#include <hip/hip_runtime.h>
#include <hip/hip_bf16.h>

#define N_H_NODES 50000
#define N_G_NODES 50000
#define N_EDGES   1600000
#define N_GRAPHS  16

typedef __bf16 bf16;
typedef __bf16 bf16x8 __attribute__((ext_vector_type(8)));
typedef __bf16 bf16x4 __attribute__((ext_vector_type(4)));
typedef float  f32x4  __attribute__((ext_vector_type(4)));

__device__ __forceinline__ bf16 f2b(float f) { return (bf16)f; }

// ---------------------------------------------------------------------------
// Weight fp32 -> bf16 pre-convert (runs every launch; ws is re-poisoned)
// ---------------------------------------------------------------------------
__global__ void convert_weights(const float* __restrict__ W1a, const float* __restrict__ W1b,
                                const float* __restrict__ W2a, const float* __restrict__ W2b,
                                bf16* __restrict__ o1a, bf16* __restrict__ o1b,
                                bf16* __restrict__ o2a, bf16* __restrict__ o2b)
{
    const int i = blockIdx.x * 256 + threadIdx.x;
    if (i < 128 * 128) {
        o1a[i] = f2b(W1a[i]);
        o1b[i] = f2b(W1b[i]);
        o2b[i] = f2b(W2b[i]);
    }
    if (i < 128 * 320) o2a[i] = f2b(W2a[i]);
}

// ---------------------------------------------------------------------------
// Counting sort of edges by tgt: histogram -> exclusive scan -> scatter perm
// (perm only; tgt of sorted edges is re-derived in the edge kernel)
// ---------------------------------------------------------------------------
__global__ void hist_kernel(const int* __restrict__ tgt, int* __restrict__ hist)
{
    const int e = blockIdx.x * 256 + threadIdx.x;
    if (e < N_EDGES) atomicAdd(&hist[tgt[e]], 1);
}

__global__ void scan_cursor(const int* __restrict__ hist, int* __restrict__ cursor)
{
    __shared__ int sums[1024];
    const int t = threadIdx.x;
    const int CH = (N_G_NODES + 1023) / 1024;   // 49
    const int base = t * CH;
    int s = 0;
    for (int i = 0; i < CH; ++i) {
        const int idx = base + i;
        if (idx < N_G_NODES) s += hist[idx];
    }
    sums[t] = s;
    __syncthreads();
    for (int off = 1; off < 1024; off <<= 1) {
        int v = (t >= off) ? sums[t - off] : 0;
        __syncthreads();
        sums[t] += v;
        __syncthreads();
    }
    int run = sums[t] - s;
    for (int i = 0; i < CH; ++i) {
        const int idx = base + i;
        if (idx < N_G_NODES) {
            cursor[idx] = run;
            run += hist[idx];
        }
    }
}

__global__ void scatter_perm(const int* __restrict__ tgt, int* __restrict__ cursor,
                             int* __restrict__ perm)
{
    const int e = blockIdx.x * 256 + threadIdx.x;
    if (e < N_EDGES) {
        const int p = atomicAdd(&cursor[tgt[e]], 1);
        perm[p] = e;
    }
}

// ---------------------------------------------------------------------------
// Edge MLP on tgt-sorted edges, minimal-LDS version.
// A and W fragments are built directly from global (x_h / edge_attr gathers,
// L2-resident bf16 weights). LDS holds only H1 (bf16 128x136 = 34.8 KB),
// overlaid by the fp32 h2 reduction tile in two 64-col chunks.
// One barrier between GEMMs; segmented reduction with wave-uniform,
// coalesced atomic flushes (~1k atomics/block).
// ---------------------------------------------------------------------------
__global__ __launch_bounds__(256, 3) void edge_mlp_fused(
    const float* __restrict__ x_h, const float* __restrict__ edge_attr,
    const float* __restrict__ b1a, const float* __restrict__ b1b,
    const bf16* __restrict__ W1a, const bf16* __restrict__ W1b,
    const int* __restrict__ src, const int* __restrict__ tgt,
    const int* __restrict__ perm, float* __restrict__ a_out)
{
    constexpr int LDA  = 136;   // bf16 H1 stride
    constexpr int LDH2 = 66;    // fp32 h2 chunk stride (64 + 2 pad)
    __shared__ __align__(16) char smem[128 * LDA * 2];   // 34816 B; chunk needs 33792 B
    bf16*  H1  = (bf16*)smem;
    float* h2s = (float*)smem;
    __shared__ int tgt_s[128];

    const int t = threadIdx.x;
    const long e0 = (long)blockIdx.x * 128;
    const int wave = t >> 6;
    const int lane = t & 63;
    const int col  = lane & 15;
    const int quad = lane >> 4;

    if (t < 128) tgt_s[t] = tgt[perm[e0 + t]];

    // per-lane edge ids / src ids for the two 16-row m-tiles
    int eA[2], sA[2];
    #pragma unroll
    for (int mi = 0; mi < 2; ++mi) {
        const int row = wave * 32 + mi * 16 + col;
        eA[mi] = perm[e0 + row];
        sA[mi] = src[eA[mi]];
    }

    f32x4 acc[2][8];
    #pragma unroll
    for (int mi = 0; mi < 2; ++mi)
        #pragma unroll
        for (int ni = 0; ni < 8; ++ni)
            acc[mi][ni] = (f32x4){0.f, 0.f, 0.f, 0.f};

    // GEMM1: h1 = [x_h[src] | edge_attr] @ W1a^T   (K = 128)
    #pragma unroll
    for (int ks = 0; ks < 4; ++ks) {
        const int k = ks * 32 + quad * 8;
        bf16x8 av[2], bv[8];
        #pragma unroll
        for (int mi = 0; mi < 2; ++mi) {
            const float* p = (ks < 2) ? (x_h + (long)sA[mi] * 64 + k)
                                      : (edge_attr + (long)eA[mi] * 64 + (k - 64));
            const float4 v0 = *(const float4*)p;
            const float4 v1 = *(const float4*)(p + 4);
            av[mi] = (bf16x8){f2b(v0.x), f2b(v0.y), f2b(v0.z), f2b(v0.w),
                              f2b(v1.x), f2b(v1.y), f2b(v1.z), f2b(v1.w)};
        }
        #pragma unroll
        for (int ni = 0; ni < 8; ++ni)
            bv[ni] = *(const bf16x8*)(W1a + (ni * 16 + col) * 128 + k);
        #pragma unroll
        for (int mi = 0; mi < 2; ++mi)
            #pragma unroll
            for (int ni = 0; ni < 8; ++ni)
                acc[mi][ni] = __builtin_amdgcn_mfma_f32_16x16x32_bf16(av[mi], bv[ni], acc[mi][ni], 0, 0, 0);
    }

    // epilogue 1: bias + leaky -> H1 (bf16)
    #pragma unroll
    for (int ni = 0; ni < 8; ++ni) {
        const float bias = b1a[ni * 16 + col];
        #pragma unroll
        for (int mi = 0; mi < 2; ++mi) {
            #pragma unroll
            for (int r = 0; r < 4; ++r) {
                float v = acc[mi][ni][r] + bias;
                v = (v >= 0.f) ? v : 0.1f * v;
                const int row = wave * 32 + mi * 16 + quad * 4 + r;
                H1[row * LDA + ni * 16 + col] = f2b(v);
            }
        }
    }
    __syncthreads();

    // GEMM2: h2 = h1 @ W1b^T   (K = 128)
    #pragma unroll
    for (int mi = 0; mi < 2; ++mi)
        #pragma unroll
        for (int ni = 0; ni < 8; ++ni)
            acc[mi][ni] = (f32x4){0.f, 0.f, 0.f, 0.f};
    #pragma unroll
    for (int ks = 0; ks < 4; ++ks) {
        const int k = ks * 32 + quad * 8;
        bf16x8 av[2], bv[8];
        #pragma unroll
        for (int mi = 0; mi < 2; ++mi)
            av[mi] = *(const bf16x8*)(&H1[(wave * 32 + mi * 16 + col) * LDA + k]);
        #pragma unroll
        for (int ni = 0; ni < 8; ++ni)
            bv[ni] = *(const bf16x8*)(W1b + (ni * 16 + col) * 128 + k);
        #pragma unroll
        for (int mi = 0; mi < 2; ++mi)
            #pragma unroll
            for (int ni = 0; ni < 8; ++ni)
                acc[mi][ni] = __builtin_amdgcn_mfma_f32_16x16x32_bf16(av[mi], bv[ni], acc[mi][ni], 0, 0, 0);
    }

    // epilogue 2: two 64-col chunks through LDS + segmented reduction.
    #pragma unroll
    for (int c = 0; c < 2; ++c) {
        __syncthreads();   // H1 / previous chunk dead
        #pragma unroll
        for (int nl = 0; nl < 4; ++nl) {
            const int ni = c * 4 + nl;
            const float bias = b1b[ni * 16 + col];
            #pragma unroll
            for (int mi = 0; mi < 2; ++mi) {
                #pragma unroll
                for (int r = 0; r < 4; ++r) {
                    const int row = wave * 32 + mi * 16 + quad * 4 + r;
                    h2s[row * LDH2 + nl * 16 + col] = acc[mi][ni][r] + bias;
                }
            }
        }
        __syncthreads();
        // 256 threads = 64 cols x 4 row-quarters; wave == quarter, so the
        // tgt-run walk is wave-uniform and flushes are 64-wide coalesced.
        {
            const int cc = t & 63;
            const int q  = t >> 6;
            float s = 0.f;
            int cur = tgt_s[q * 32];
            #pragma unroll 8
            for (int i = 0; i < 32; ++i) {
                const int tg = tgt_s[q * 32 + i];
                if (tg != cur) {
                    atomicAdd(&a_out[(long)cur * 128 + c * 64 + cc], s);
                    s = 0.f;
                    cur = tg;
                }
                s += h2s[(q * 32 + i) * LDH2 + cc];
            }
            atomicAdd(&a_out[(long)cur * 128 + c * 64 + cc], s);
        }
    }
}

// ---------------------------------------------------------------------------
// Node MLP: A-fragments built directly from global fp32 (x_g | a | u[batch]),
// weights read from L2-resident bf16; only H1 lives in LDS (34.8 KB)
// ---------------------------------------------------------------------------
__global__ __launch_bounds__(256, 4) void node_mlp2(
    const float* __restrict__ x_g, const float* __restrict__ u,
    const float* __restrict__ b2a, const float* __restrict__ b2b,
    const bf16* __restrict__ W2a, const bf16* __restrict__ W2b,
    const int* __restrict__ batch_g, const float* __restrict__ a_in,
    float* __restrict__ out)
{
    constexpr int LDH = 136;
    __shared__ __align__(16) bf16 H1[128 * LDH];

    const int t = threadIdx.x;
    const int n0 = blockIdx.x * 128;
    const int wave = t >> 6;
    const int lane = t & 63;
    const int col  = lane & 15;
    const int quad = lane >> 4;

    int grow[2];
    int bg[2];
    #pragma unroll
    for (int mi = 0; mi < 2; ++mi) {
        const int r = n0 + wave * 32 + mi * 16 + col;
        grow[mi] = min(r, N_G_NODES - 1);
        bg[mi] = batch_g[grow[mi]];
    }

    f32x4 acc[2][8];
    #pragma unroll
    for (int mi = 0; mi < 2; ++mi)
        #pragma unroll
        for (int ni = 0; ni < 8; ++ni)
            acc[mi][ni] = (f32x4){0.f, 0.f, 0.f, 0.f};

    // GEMM1: K=320
    #pragma unroll
    for (int ks = 0; ks < 10; ++ks) {
        const int k = ks * 32 + quad * 8;
        bf16x8 av[2], bv[8];
        #pragma unroll
        for (int mi = 0; mi < 2; ++mi) {
            const float* p;
            if (k < 128)      p = x_g  + (long)grow[mi] * 128 + k;
            else if (k < 256) p = a_in + (long)grow[mi] * 128 + (k - 128);
            else              p = u + bg[mi] * 64 + (k - 256);
            const float4 v0 = *(const float4*)p;
            const float4 v1 = *(const float4*)(p + 4);
            av[mi] = (bf16x8){f2b(v0.x), f2b(v0.y), f2b(v0.z), f2b(v0.w),
                              f2b(v1.x), f2b(v1.y), f2b(v1.z), f2b(v1.w)};
        }
        #pragma unroll
        for (int ni = 0; ni < 8; ++ni)
            bv[ni] = *(const bf16x8*)(W2a + (long)(ni * 16 + col) * 320 + k);
        #pragma unroll
        for (int mi = 0; mi < 2; ++mi)
            #pragma unroll
            for (int ni = 0; ni < 8; ++ni)
                acc[mi][ni] = __builtin_amdgcn_mfma_f32_16x16x32_bf16(av[mi], bv[ni], acc[mi][ni], 0, 0, 0);
    }

    // epilogue 1 -> H1 (bf16)
    #pragma unroll
    for (int ni = 0; ni < 8; ++ni) {
        const float bias = b2a[ni * 16 + col];
        #pragma unroll
        for (int mi = 0; mi < 2; ++mi) {
            #pragma unroll
            for (int r = 0; r < 4; ++r) {
                float v = acc[mi][ni][r] + bias;
                v = (v >= 0.f) ? v : 0.1f * v;
                const int row = wave * 32 + mi * 16 + quad * 4 + r;
                H1[row * LDH + ni * 16 + col] = f2b(v);
            }
        }
    }
    __syncthreads();

    // GEMM2: K=128
    #pragma unroll
    for (int mi = 0; mi < 2; ++mi)
        #pragma unroll
        for (int ni = 0; ni < 8; ++ni)
            acc[mi][ni] = (f32x4){0.f, 0.f, 0.f, 0.f};
    #pragma unroll
    for (int ks = 0; ks < 4; ++ks) {
        bf16x8 av[2], bv[8];
        #pragma unroll
        for (int mi = 0; mi < 2; ++mi)
            av[mi] = *(const bf16x8*)(&H1[(wave * 32 + mi * 16 + col) * LDH + ks * 32 + quad * 8]);
        #pragma unroll
        for (int ni = 0; ni < 8; ++ni)
            bv[ni] = *(const bf16x8*)(W2b + (long)(ni * 16 + col) * 128 + ks * 32 + quad * 8);
        #pragma unroll
        for (int mi = 0; mi < 2; ++mi)
            #pragma unroll
            for (int ni = 0; ni < 8; ++ni)
                acc[mi][ni] = __builtin_amdgcn_mfma_f32_16x16x32_bf16(av[mi], bv[ni], acc[mi][ni], 0, 0, 0);
    }

    // epilogue 2: bias + store (row-guarded)
    #pragma unroll
    for (int ni = 0; ni < 8; ++ni) {
        const float bias = b2b[ni * 16 + col];
        #pragma unroll
        for (int mi = 0; mi < 2; ++mi) {
            #pragma unroll
            for (int r = 0; r < 4; ++r) {
                const int row = wave * 32 + mi * 16 + quad * 4 + r;
                const int g = n0 + row;
                if (g < N_G_NODES)
                    out[(long)g * 128 + ni * 16 + col] = acc[mi][ni][r] + bias;
            }
        }
    }
}

// ---------------------------------------------------------------------------
extern "C" void kernel_launch(void* const* d_in, const int* in_sizes, int n_in,
                              void* d_out, int out_size, void* d_ws, size_t ws_size,
                              hipStream_t stream)
{
    const float* x_h  = (const float*)d_in[0];
    const float* x_g  = (const float*)d_in[1];
    const float* edge_attr = (const float*)d_in[2];
    const float* u    = (const float*)d_in[3];
    const float* W1a  = (const float*)d_in[4];
    const float* b1a  = (const float*)d_in[5];
    const float* W1b  = (const float*)d_in[6];
    const float* b1b  = (const float*)d_in[7];
    const float* W2a  = (const float*)d_in[8];
    const float* b2a  = (const float*)d_in[9];
    const float* W2b  = (const float*)d_in[10];
    const float* b2b  = (const float*)d_in[11];
    const int* edge_index = (const int*)d_in[12];   // [2, E]
    const int* batch_g    = (const int*)d_in[13];
    const int* src = edge_index;
    const int* tgt = edge_index + N_EDGES;

    char* ws = (char*)d_ws;
    size_t off = 0;
    float* a_acc = (float*)(ws + off); off += (size_t)N_G_NODES * 128 * sizeof(float);
    bf16* w1a = (bf16*)(ws + off); off += (size_t)128 * 128 * sizeof(bf16);
    bf16* w1b = (bf16*)(ws + off); off += (size_t)128 * 128 * sizeof(bf16);
    bf16* w2a = (bf16*)(ws + off); off += (size_t)128 * 320 * sizeof(bf16);
    bf16* w2b = (bf16*)(ws + off); off += (size_t)128 * 128 * sizeof(bf16);
    int* hist   = (int*)(ws + off); off += (size_t)N_G_NODES * sizeof(int);
    int* cursor = (int*)(ws + off); off += (size_t)N_G_NODES * sizeof(int);
    int* perm   = (int*)(ws + off); off += (size_t)N_EDGES * sizeof(int);

    hipMemsetAsync(a_acc, 0, (size_t)N_G_NODES * 128 * sizeof(float), stream);
    hipMemsetAsync(hist, 0, (size_t)N_G_NODES * sizeof(int), stream);

    convert_weights<<<160, 256, 0, stream>>>(W1a, W1b, W2a, W2b, w1a, w1b, w2a, w2b);
    hist_kernel<<<(N_EDGES + 255) / 256, 256, 0, stream>>>(tgt, hist);
    scan_cursor<<<1, 1024, 0, stream>>>(hist, cursor);
    scatter_perm<<<(N_EDGES + 255) / 256, 256, 0, stream>>>(tgt, cursor, perm);
    edge_mlp_fused<<<N_EDGES / 128, 256, 0, stream>>>(x_h, edge_attr, b1a, b1b,
                                                      w1a, w1b, src, tgt, perm, a_acc);
    node_mlp2<<<(N_G_NODES + 127) / 128, 256, 0, stream>>>(x_g, u, b2a, b2b,
                                                           w2a, w2b, batch_g, a_acc,
                                                           (float*)d_out);
}